// Round 9
// baseline (998.747 us; speedup 1.0000x reference)
//
#include <hip/hip_runtime.h>

#define NNODES 50000
#define NPAD   50048   // 391 * 128
#define NEDGES 800000
#define HDIM 128
#define OUTDIM 64

typedef short short8 __attribute__((ext_vector_type(8)));
typedef _Float16 half8 __attribute__((ext_vector_type(8)));
typedef float f32x4 __attribute__((ext_vector_type(4)));
typedef _Float16 f16x2 __attribute__((ext_vector_type(2)));
typedef unsigned short us4 __attribute__((ext_vector_type(4)));

__device__ __forceinline__ unsigned short f2bf(float f) {
    unsigned int u = __builtin_bit_cast(unsigned int, f);
    unsigned int r = (u + 0x7FFFu + ((u >> 16) & 1u)) >> 16;
    return (unsigned short)r;
}
__device__ __forceinline__ float bf2f(unsigned short b) {
    unsigned int u = ((unsigned int)b) << 16;
    return __builtin_bit_cast(float, u);
}

// ---------------- CSR build ----------------
__global__ void count_kernel(const int* __restrict__ dst, int* __restrict__ deg,
                             unsigned short* __restrict__ epos) {
    int e = blockIdx.x * 256 + threadIdx.x;
    if (e < NEDGES) epos[e] = (unsigned short)atomicAdd(&deg[dst[e]], 1);
}

// 196 blocks; device-scope ticket merges bsum+bscan+emit into one kernel.
// ready/flag must be pre-zeroed (memset with deg).
__global__ __launch_bounds__(256) void scan_emit_kernel(
    const int* __restrict__ deg, int* __restrict__ bsum, int* __restrict__ bofs,
    int* __restrict__ ready, int* __restrict__ flag,
    int* __restrict__ row_ptr, float* __restrict__ norm) {
    __shared__ int s[256];
    __shared__ int bcast;
    const int t = threadIdx.x;
    const int i = blockIdx.x * 256 + t;
    const int v = (i < NNODES) ? deg[i] : 0;
    s[t] = v;
    __syncthreads();
    for (int off = 1; off < 256; off <<= 1) {
        int u = (t >= off) ? s[t - off] : 0;
        __syncthreads();
        s[t] += u;
        __syncthreads();
    }
    const int incl = s[t];
    const int total = s[255];
    if (t == 0) {
        bsum[blockIdx.x] = total;
        __threadfence();
        int r = __hip_atomic_fetch_add(ready, 1, __ATOMIC_ACQ_REL, __HIP_MEMORY_SCOPE_AGENT);
        if (r == 195) {  // last arriver: scan the 196 block sums
            int run = 0;
            for (int j = 0; j < 196; ++j) { bofs[j] = run; run += bsum[j]; }
            __threadfence();
            __hip_atomic_store(flag, 1, __ATOMIC_RELEASE, __HIP_MEMORY_SCOPE_AGENT);
        }
        while (__hip_atomic_load(flag, __ATOMIC_ACQUIRE, __HIP_MEMORY_SCOPE_AGENT) != 1) {}
        bcast = bofs[blockIdx.x];
    }
    __syncthreads();
    const int excl = incl - v + bcast;
    if (i < NNODES) {
        row_ptr[i] = excl;
        norm[i] = rsqrtf(1.0f + (float)v);
    }
    if (i == NNODES - 1) row_ptr[NNODES] = NEDGES;
}

__global__ void fill_kernel(const int* __restrict__ src, const int* __restrict__ dst,
                            const unsigned short* __restrict__ epos,
                            const int* __restrict__ row_ptr,
                            unsigned short* __restrict__ sorted_src) {
    int e = blockIdx.x * 256 + threadIdx.x;
    if (e < NEDGES)
        sorted_src[row_ptr[dst[e]] + (int)epos[e]] = (unsigned short)src[e];
}

// ---------------- weight prep ----------------
// bf16 hi/lo (wT): w_in slot 0, w1[m] slot 1+m, w_out slot 7 (64 rows).
// f16 single (w2f): w2[m] at m*16384, layout [n][128].
__global__ __launch_bounds__(256) void prep_w_kernel(
    const float* __restrict__ w_in, const float* __restrict__ w1,
    const float* __restrict__ w2, const float* __restrict__ w_out,
    unsigned short* __restrict__ wT, _Float16* __restrict__ w2f) {
    int idx = blockIdx.x * 256 + threadIdx.x;  // total 221184 = 864*256
    if (idx < 16384 + 98304) {
        const float* W;
        unsigned short* o;
        int e;
        if (idx < 16384) {
            W = w_in; o = wT; e = idx;
        } else {
            int j = idx - 16384; int m = j >> 14; e = j & 16383;
            W = w1 + ((size_t)m << 14); o = wT + (size_t)(1 + m) * 32768;
        }
        int k = e >> 7, n = e & 127;
        float v = W[e];
        unsigned short h = f2bf(v);
        o[(size_t)n * 256 + k] = h;
        o[(size_t)n * 256 + 128 + k] = f2bf(v - bf2f(h));
    } else if (idx < 16384 + 196608) {
        int j = idx - 16384 - 98304; int m = j >> 14; int e = j & 16383;
        int k = e >> 7, n = e & 127;
        w2f[(size_t)m * 16384 + n * 128 + k] = (_Float16)w2[((size_t)m << 14) + e];
    } else {
        int e = idx - 212992;  // w_out: 8192 elements
        int k = e >> 6, n = e & 63;
        float v = w_out[e];
        unsigned short h = f2bf(v);
        unsigned short* o = wT + (size_t)7 * 32768;
        o[(size_t)n * 256 + k] = h;
        o[(size_t)n * 256 + 128 + k] = f2bf(v - bf2f(h));
    }
}

// ---------------- input GEMM: fp32 A staged + in-reg hi/lo split -------------
// y16 = (inputs @ W_in) * norm. 4 chunks of 32 fp32 K-cols; per chunk
// MFMA sets: Ahi@Whi + Ahi@Wlo + Alo@Whi.
__global__ __launch_bounds__(256) void gemm_in_kernel(
    const float* __restrict__ inp, const unsigned short* __restrict__ wT,
    const float* __restrict__ norm, _Float16* __restrict__ y) {
    __shared__ unsigned short Ahi[128 * 32];
    __shared__ unsigned short Alo[128 * 32];
    __shared__ unsigned short B1[128 * 32];
    __shared__ unsigned short B2[128 * 32];
    const int t = threadIdx.x;
    const int wave = t >> 6, lane = t & 63, quad = lane >> 4, l16 = lane & 15;
    const int row0 = blockIdx.x * 128;
    const int wm = (wave >> 1) * 64;
    const int wn = (wave & 1) * 64;

    f32x4 acc[4][4];
#pragma unroll
    for (int mt = 0; mt < 4; ++mt)
#pragma unroll
        for (int nt = 0; nt < 4; ++nt) acc[mt][nt] = (f32x4){0.f, 0.f, 0.f, 0.f};

    for (int ks = 0; ks < 4; ++ks) {
        const int k0 = ks * 32;
        __syncthreads();
        // A: 128 rows x 32 fp32 cols = 1024 float4 chunks; convert to hi/lo
#pragma unroll
        for (int i = 0; i < 4; ++i) {
            int c = i * 256 + t;
            int m = c >> 3, q = c & 7;
            int row = row0 + m;
            float4 v = {0.f, 0.f, 0.f, 0.f};
            if (row < NNODES) v = *(const float4*)(inp + (size_t)row * 128 + k0 + q * 4);
            float vv[4] = {v.x, v.y, v.z, v.w};
            us4 hi, lo;
#pragma unroll
            for (int j = 0; j < 4; ++j) {
                unsigned short h = f2bf(vv[j]);
                hi[j] = h;
                lo[j] = f2bf(vv[j] - bf2f(h));
            }
            *(us4*)(Ahi + m * 32 + q * 4) = hi;
            *(us4*)(Alo + m * 32 + q * 4) = lo;
        }
        // B: Whi + Wlo chunks via global_load_lds
#pragma unroll
        for (int i = 0; i < 2; ++i) {
            int c = i * 256 + t;
            int n = c >> 2, q = c & 3;
            __builtin_amdgcn_global_load_lds(
                (const __attribute__((address_space(1))) void*)(wT + (size_t)n * 256 + k0 + q * 8),
                (__attribute__((address_space(3))) void*)(B1 + (size_t)c * 8), 16, 0, 0);
        }
#pragma unroll
        for (int i = 0; i < 2; ++i) {
            int c = i * 256 + t;
            int n = c >> 2, q = c & 3;
            __builtin_amdgcn_global_load_lds(
                (const __attribute__((address_space(1))) void*)(wT + (size_t)n * 256 + 128 + k0 + q * 8),
                (__attribute__((address_space(3))) void*)(B2 + (size_t)c * 8), 16, 0, 0);
        }
        __syncthreads();

        short8 ah[4], al[4], b1[4], b2[4];
#pragma unroll
        for (int mt = 0; mt < 4; ++mt) {
            ah[mt] = *(const short8*)(Ahi + (size_t)(wm + mt * 16 + l16) * 32 + quad * 8);
            al[mt] = *(const short8*)(Alo + (size_t)(wm + mt * 16 + l16) * 32 + quad * 8);
        }
#pragma unroll
        for (int nt = 0; nt < 4; ++nt) {
            b1[nt] = *(const short8*)(B1 + (size_t)(wn + nt * 16 + l16) * 32 + quad * 8);
            b2[nt] = *(const short8*)(B2 + (size_t)(wn + nt * 16 + l16) * 32 + quad * 8);
        }
#pragma unroll
        for (int mt = 0; mt < 4; ++mt)
#pragma unroll
            for (int nt = 0; nt < 4; ++nt) {
                acc[mt][nt] = __builtin_amdgcn_mfma_f32_16x16x32_bf16(ah[mt], b1[nt], acc[mt][nt], 0, 0, 0);
                acc[mt][nt] = __builtin_amdgcn_mfma_f32_16x16x32_bf16(ah[mt], b2[nt], acc[mt][nt], 0, 0, 0);
                acc[mt][nt] = __builtin_amdgcn_mfma_f32_16x16x32_bf16(al[mt], b1[nt], acc[mt][nt], 0, 0, 0);
            }
    }

#pragma unroll
    for (int mt = 0; mt < 4; ++mt) {
        int mbase = row0 + wm + mt * 16 + quad * 4;
#pragma unroll
        for (int r = 0; r < 4; ++r) {
            int row = mbase + r;
            if (row < NNODES) {
                float nm = norm[row];
#pragma unroll
                for (int nt = 0; nt < 4; ++nt) {
                    int col = wn + nt * 16 + l16;
                    y[(size_t)row * 128 + col] = (_Float16)(acc[mt][nt][r] * nm);
                }
            }
        }
    }
}

// ---------------- bf16 hi/lo MFMA GEMM: y16 = ((hi+lo)@W)*norm ----------------
template <int NCOLS>
__global__ __launch_bounds__(256) void gemm_bf_kernel(
    const unsigned short* __restrict__ xc, const unsigned short* __restrict__ wT,
    const float* __restrict__ norm, _Float16* __restrict__ y) {
    constexpr int MT = (NCOLS == 128) ? 4 : 2;
    __shared__ unsigned short Alds[128 * 32];
    __shared__ unsigned short B1lds[NCOLS * 32];
    __shared__ unsigned short B2lds[NCOLS * 32];
    const int t = threadIdx.x;
    const int wave = t >> 6, lane = t & 63, quad = lane >> 4, l16 = lane & 15;
    const int row0 = blockIdx.x * 128;
    const int wm = (NCOLS == 128) ? (wave >> 1) * 64 : wave * 32;
    const int wn = (NCOLS == 128) ? (wave & 1) * 64 : 0;

    f32x4 acc[MT][4];
#pragma unroll
    for (int mt = 0; mt < MT; ++mt)
#pragma unroll
        for (int nt = 0; nt < 4; ++nt) acc[mt][nt] = (f32x4){0.f, 0.f, 0.f, 0.f};

    for (int ks = 0; ks < 8; ++ks) {
        const int k0 = ks * 32;
        const int kb = (ks < 4) ? k0 : (k0 - 128);
        __syncthreads();
#pragma unroll
        for (int i = 0; i < 2; ++i) {
            int c = i * 256 + t;
            int m = c >> 2, q = c & 3;
            const unsigned short* gp = xc + (size_t)(row0 + m) * 256 + k0 + q * 8;
            unsigned short* lp = Alds + (size_t)c * 8;
            __builtin_amdgcn_global_load_lds(
                (const __attribute__((address_space(1))) void*)gp,
                (__attribute__((address_space(3))) void*)lp, 16, 0, 0);
        }
#pragma unroll
        for (int i = 0; i < (NCOLS * 4) / 256; ++i) {
            int c = i * 256 + t;
            int n = c >> 2, q = c & 3;
            const unsigned short* gp = wT + (size_t)n * 256 + kb + q * 8;
            unsigned short* lp = B1lds + (size_t)c * 8;
            __builtin_amdgcn_global_load_lds(
                (const __attribute__((address_space(1))) void*)gp,
                (__attribute__((address_space(3))) void*)lp, 16, 0, 0);
        }
        if (ks < 4) {
#pragma unroll
            for (int i = 0; i < (NCOLS * 4) / 256; ++i) {
                int c = i * 256 + t;
                int n = c >> 2, q = c & 3;
                const unsigned short* gp = wT + (size_t)n * 256 + 128 + k0 + q * 8;
                unsigned short* lp = B2lds + (size_t)c * 8;
                __builtin_amdgcn_global_load_lds(
                    (const __attribute__((address_space(1))) void*)gp,
                    (__attribute__((address_space(3))) void*)lp, 16, 0, 0);
            }
        }
        __syncthreads();

        short8 a[MT], b1[4];
#pragma unroll
        for (int mt = 0; mt < MT; ++mt)
            a[mt] = *(const short8*)(Alds + (size_t)(wm + mt * 16 + l16) * 32 + quad * 8);
#pragma unroll
        for (int nt = 0; nt < 4; ++nt)
            b1[nt] = *(const short8*)(B1lds + (size_t)(wn + nt * 16 + l16) * 32 + quad * 8);
#pragma unroll
        for (int mt = 0; mt < MT; ++mt)
#pragma unroll
            for (int nt = 0; nt < 4; ++nt)
                acc[mt][nt] = __builtin_amdgcn_mfma_f32_16x16x32_bf16(
                    a[mt], b1[nt], acc[mt][nt], 0, 0, 0);
        if (ks < 4) {
            short8 b2[4];
#pragma unroll
            for (int nt = 0; nt < 4; ++nt)
                b2[nt] = *(const short8*)(B2lds + (size_t)(wn + nt * 16 + l16) * 32 + quad * 8);
#pragma unroll
            for (int mt = 0; mt < MT; ++mt)
#pragma unroll
                for (int nt = 0; nt < 4; ++nt)
                    acc[mt][nt] = __builtin_amdgcn_mfma_f32_16x16x32_bf16(
                        a[mt], b2[nt], acc[mt][nt], 0, 0, 0);
        }
    }

#pragma unroll
    for (int mt = 0; mt < MT; ++mt) {
        int mbase = row0 + wm + mt * 16 + quad * 4;
#pragma unroll
        for (int r = 0; r < 4; ++r) {
            int row = mbase + r;
            if (row < NNODES) {
                float nm = norm[row];
#pragma unroll
                for (int nt = 0; nt < 4; ++nt) {
                    int col = wn + nt * 16 + l16;
                    y[(size_t)row * NCOLS + col] = (_Float16)(acc[mt][nt][r] * nm);
                }
            }
        }
    }
}

// ---------------- f16 MFMA GEMM (x-conv): y16 = (h16 @ W2f)*norm -------------
__global__ __launch_bounds__(256) void gemm_f16_kernel(
    const _Float16* __restrict__ A, const _Float16* __restrict__ wf,
    const float* __restrict__ norm, _Float16* __restrict__ y) {
    __shared__ _Float16 Alds[128 * 32];
    __shared__ _Float16 Blds[128 * 32];
    const int t = threadIdx.x;
    const int wave = t >> 6, lane = t & 63, quad = lane >> 4, l16 = lane & 15;
    const int row0 = blockIdx.x * 128;
    const int wm = (wave >> 1) * 64;
    const int wn = (wave & 1) * 64;

    f32x4 acc[4][4];
#pragma unroll
    for (int mt = 0; mt < 4; ++mt)
#pragma unroll
        for (int nt = 0; nt < 4; ++nt) acc[mt][nt] = (f32x4){0.f, 0.f, 0.f, 0.f};

    for (int ks = 0; ks < 4; ++ks) {
        const int k0 = ks * 32;
        __syncthreads();
#pragma unroll
        for (int i = 0; i < 2; ++i) {
            int c = i * 256 + t;
            int m = c >> 2, q = c & 3;
            const _Float16* gp = A + (size_t)(row0 + m) * 128 + k0 + q * 8;
            _Float16* lp = Alds + (size_t)c * 8;
            __builtin_amdgcn_global_load_lds(
                (const __attribute__((address_space(1))) void*)gp,
                (__attribute__((address_space(3))) void*)lp, 16, 0, 0);
        }
#pragma unroll
        for (int i = 0; i < 2; ++i) {
            int c = i * 256 + t;
            int n = c >> 2, q = c & 3;
            const _Float16* gp = wf + (size_t)n * 128 + k0 + q * 8;
            _Float16* lp = Blds + (size_t)c * 8;
            __builtin_amdgcn_global_load_lds(
                (const __attribute__((address_space(1))) void*)gp,
                (__attribute__((address_space(3))) void*)lp, 16, 0, 0);
        }
        __syncthreads();

        half8 a[4], b[4];
#pragma unroll
        for (int mt = 0; mt < 4; ++mt)
            a[mt] = *(const half8*)(Alds + (size_t)(wm + mt * 16 + l16) * 32 + quad * 8);
#pragma unroll
        for (int nt = 0; nt < 4; ++nt)
            b[nt] = *(const half8*)(Blds + (size_t)(wn + nt * 16 + l16) * 32 + quad * 8);
#pragma unroll
        for (int mt = 0; mt < 4; ++mt)
#pragma unroll
            for (int nt = 0; nt < 4; ++nt)
                acc[mt][nt] = __builtin_amdgcn_mfma_f32_16x16x32_f16(
                    a[mt], b[nt], acc[mt][nt], 0, 0, 0);
    }

#pragma unroll
    for (int mt = 0; mt < 4; ++mt) {
        int mbase = row0 + wm + mt * 16 + quad * 4;
#pragma unroll
        for (int r = 0; r < 4; ++r) {
            int row = mbase + r;
            if (row < NNODES) {
                float nm = norm[row];
#pragma unroll
                for (int nt = 0; nt < 4; ++nt) {
                    int col = wn + nt * 16 + l16;
                    y[(size_t)row * 128 + col] = (_Float16)(acc[mt][nt][r] * nm);
                }
            }
        }
    }
}

// ---------------- fused gather + finalize (F=128, fp16 y) ----------------
// MODE 0: plain leaky; 1: residual from xcres (hi/lo bf16).
// OUT16: write h16 (f16 single); else write xcout (bf16 hi/lo).
// WOUT: also write fp32 out.
template <int MODE, bool WOUT, bool OUT16>
__global__ __launch_bounds__(256) void gather_fin128(
    const _Float16* __restrict__ y, const int* __restrict__ row_ptr,
    const unsigned short* __restrict__ sorted_src, const float* __restrict__ norm,
    const float* __restrict__ bias, const unsigned short* __restrict__ xcres,
    float* __restrict__ out, unsigned short* __restrict__ xcout,
    _Float16* __restrict__ h16) {
    const int wave = threadIdx.x >> 6;
    const int lane = threadIdx.x & 63;
    const int n = blockIdx.x * 4 + wave;
    const int beg = row_ptr[n];
    const int end = row_ptr[n + 1];

    float2 a0 = {0.f, 0.f}, a1 = a0, a2 = a0, a3 = a0, a4 = a0, a5 = a0, a6 = a0, a7 = a0;
    int i = beg;
    for (; i + 7 < end; i += 8) {
        int s0 = sorted_src[i], s1 = sorted_src[i + 1];
        int s2 = sorted_src[i + 2], s3 = sorted_src[i + 3];
        int s4 = sorted_src[i + 4], s5 = sorted_src[i + 5];
        int s6 = sorted_src[i + 6], s7 = sorted_src[i + 7];
        f16x2 h0 = *(const f16x2*)(y + (size_t)s0 * 128 + lane * 2);
        f16x2 h1 = *(const f16x2*)(y + (size_t)s1 * 128 + lane * 2);
        f16x2 h2 = *(const f16x2*)(y + (size_t)s2 * 128 + lane * 2);
        f16x2 h3 = *(const f16x2*)(y + (size_t)s3 * 128 + lane * 2);
        f16x2 h4 = *(const f16x2*)(y + (size_t)s4 * 128 + lane * 2);
        f16x2 h5 = *(const f16x2*)(y + (size_t)s5 * 128 + lane * 2);
        f16x2 h6 = *(const f16x2*)(y + (size_t)s6 * 128 + lane * 2);
        f16x2 h7 = *(const f16x2*)(y + (size_t)s7 * 128 + lane * 2);
        a0.x += (float)h0.x; a0.y += (float)h0.y;
        a1.x += (float)h1.x; a1.y += (float)h1.y;
        a2.x += (float)h2.x; a2.y += (float)h2.y;
        a3.x += (float)h3.x; a3.y += (float)h3.y;
        a4.x += (float)h4.x; a4.y += (float)h4.y;
        a5.x += (float)h5.x; a5.y += (float)h5.y;
        a6.x += (float)h6.x; a6.y += (float)h6.y;
        a7.x += (float)h7.x; a7.y += (float)h7.y;
    }
    for (; i < end; ++i) {
        int s = sorted_src[i];
        f16x2 h = *(const f16x2*)(y + (size_t)s * 128 + lane * 2);
        a0.x += (float)h.x; a0.y += (float)h.y;
    }
    a0.x += a1.x; a0.y += a1.y;
    a2.x += a3.x; a2.y += a3.y;
    a4.x += a5.x; a4.y += a5.y;
    a6.x += a7.x; a6.y += a7.y;
    a0.x += a2.x; a0.y += a2.y;
    a4.x += a6.x; a4.y += a6.y;
    a0.x += a4.x; a0.y += a4.y;

    const f16x2 sh = *(const f16x2*)(y + (size_t)n * 128 + lane * 2);
    const float2 bi = *(const float2*)(bias + lane * 2);
    const float nm = norm[n];
    float v0 = (a0.x + (float)sh.x) * nm + bi.x;
    float v1 = (a0.y + (float)sh.y) * nm + bi.y;
    v0 = v0 >= 0.f ? v0 : 0.01f * v0;
    v1 = v1 >= 0.f ? v1 : 0.01f * v1;
    if (MODE == 1) {
        unsigned int hw = *(const unsigned int*)(xcres + (size_t)n * 256 + lane * 2);
        unsigned int lw = *(const unsigned int*)(xcres + (size_t)n * 256 + 128 + lane * 2);
        float xr0 = bf2f((unsigned short)hw) + bf2f((unsigned short)lw);
        float xr1 = bf2f((unsigned short)(hw >> 16)) + bf2f((unsigned short)(lw >> 16));
        v0 = (xr0 + v0) * 0.5f;
        v1 = (xr1 + v1) * 0.5f;
    }
    if (WOUT) {
        float2 o = {v0, v1};
        *(float2*)(out + (size_t)n * 128 + lane * 2) = o;
    }
    if (OUT16) {
        f16x2 o16 = {(_Float16)v0, (_Float16)v1};
        *(f16x2*)(h16 + (size_t)n * 128 + lane * 2) = o16;
    } else {
        unsigned short h0 = f2bf(v0), h1 = f2bf(v1);
        unsigned short l0 = f2bf(v0 - bf2f(h0)), l1 = f2bf(v1 - bf2f(h1));
        *(unsigned int*)(xcout + (size_t)n * 256 + lane * 2) =
            (unsigned int)h0 | ((unsigned int)h1 << 16);
        *(unsigned int*)(xcout + (size_t)n * 256 + 128 + lane * 2) =
            (unsigned int)l0 | ((unsigned int)l1 << 16);
    }
}

// ---------------- final gather (F=64, identity, fp16 y) ----------------
__global__ __launch_bounds__(256) void gather_fin64(
    const _Float16* __restrict__ y, const int* __restrict__ row_ptr,
    const unsigned short* __restrict__ sorted_src, const float* __restrict__ norm,
    const float* __restrict__ bias, float* __restrict__ out) {
    const int wave = threadIdx.x >> 6;
    const int lane = threadIdx.x & 63;
    const int n = blockIdx.x * 4 + wave;
    const int beg = row_ptr[n];
    const int end = row_ptr[n + 1];
    float a0 = 0.f, a1 = 0.f, a2 = 0.f, a3 = 0.f;
    int i = beg;
    for (; i + 3 < end; i += 4) {
        int s0 = sorted_src[i], s1 = sorted_src[i + 1];
        int s2 = sorted_src[i + 2], s3 = sorted_src[i + 3];
        a0 += (float)y[(size_t)s0 * 64 + lane];
        a1 += (float)y[(size_t)s1 * 64 + lane];
        a2 += (float)y[(size_t)s2 * 64 + lane];
        a3 += (float)y[(size_t)s3 * 64 + lane];
    }
    for (; i < end; ++i) a0 += (float)y[(size_t)sorted_src[i] * 64 + lane];
    a0 += a1; a2 += a3; a0 += a2;
    float self = (float)y[(size_t)n * 64 + lane];
    out[(size_t)n * 64 + lane] = (a0 + self) * norm[n] + bias[lane];
}

extern "C" void kernel_launch(void* const* d_in, const int* in_sizes, int n_in,
                              void* d_out, int out_size, void* d_ws, size_t ws_size,
                              hipStream_t stream) {
    const float* inputs = (const float*)d_in[0];
    const int* edges = (const int*)d_in[1];
    const int* src = edges;
    const int* dst = edges + NEDGES;
    const float* w_in  = (const float*)d_in[2];
    const float* b_in  = (const float*)d_in[3];
    const float* w1    = (const float*)d_in[4];
    const float* b1    = (const float*)d_in[5];
    const float* w2    = (const float*)d_in[6];
    const float* b2    = (const float*)d_in[7];
    const float* w_out = (const float*)d_in[8];
    const float* b_out = (const float*)d_in[9];

    float* out  = (float*)d_out;
    float* xout = out;                                // [N, 64]
    float* x    = out + (size_t)NNODES * OUTDIM;      // [N, 128] fp32 x (final only)

    char* p = (char*)d_ws;
    auto alloc = [&](size_t bytes) {
        char* r = p;
        p += (bytes + 63) & ~(size_t)63;
        return r;
    };
    int* deg        = (int*)alloc((NNODES + 2) * 4);  // deg | ready | flag
    int* ready      = deg + NNODES;
    int* flag       = deg + NNODES + 1;
    unsigned short* epos = (unsigned short*)alloc(NEDGES * 2);
    int* row_ptr    = (int*)alloc((NNODES + 1) * 4);
    int* bsum       = (int*)alloc(256 * 4);
    int* bofs       = (int*)alloc(256 * 4);
    unsigned short* sorted_src = (unsigned short*)alloc(NEDGES * 2);
    float* normb    = (float*)alloc(NNODES * 4);
    unsigned short* wT = (unsigned short*)alloc((size_t)245760 * 2);  // 7*32768+16384
    _Float16* w2f   = (_Float16*)alloc((size_t)6 * 16384 * 2);
    unsigned short* xc_x = (unsigned short*)alloc((size_t)NPAD * 256 * 2);
    _Float16* h16   = (_Float16*)alloc((size_t)NPAD * 128 * 2);
    _Float16* y     = (_Float16*)alloc((size_t)NNODES * HDIM * 2);

    // ---- CSR + norm + weight prep ----
    hipMemsetAsync(deg, 0, (NNODES + 2) * sizeof(int), stream);
    count_kernel<<<(NEDGES + 255) / 256, 256, 0, stream>>>(dst, deg, epos);
    scan_emit_kernel<<<196, 256, 0, stream>>>(deg, bsum, bofs, ready, flag, row_ptr, normb);
    fill_kernel<<<(NEDGES + 255) / 256, 256, 0, stream>>>(src, dst, epos, row_ptr, sorted_src);
    prep_w_kernel<<<864, 256, 0, stream>>>(w_in, w1, w2, w_out, wT, w2f);

    // input layer: fp32-A GEMM (split fused), gather -> xc_x
    gemm_in_kernel<<<NPAD / 128, 256, 0, stream>>>(inputs, wT, normb, y);
    gather_fin128<0, false, false><<<NNODES / 4, 256, 0, stream>>>(
        y, row_ptr, sorted_src, normb, b_in, nullptr, nullptr, xc_x, nullptr);

    // 6 residual blocks
    for (int i = 0; i < 6; ++i) {
        gemm_bf_kernel<128><<<NPAD / 128, 256, 0, stream>>>(
            xc_x, wT + (size_t)(1 + i) * 32768, normb, y);
        gather_fin128<0, false, true><<<NNODES / 4, 256, 0, stream>>>(
            y, row_ptr, sorted_src, normb, b1 + i * HDIM, nullptr, nullptr, nullptr, h16);
        gemm_f16_kernel<<<NPAD / 128, 256, 0, stream>>>(
            h16, w2f + (size_t)i * 16384, normb, y);
        if (i < 5)
            gather_fin128<1, false, false><<<NNODES / 4, 256, 0, stream>>>(
                y, row_ptr, sorted_src, normb, b2 + i * HDIM, xc_x, nullptr, xc_x, nullptr);
        else
            gather_fin128<1, true, false><<<NNODES / 4, 256, 0, stream>>>(
                y, row_ptr, sorted_src, normb, b2 + i * HDIM, xc_x, x, xc_x, nullptr);
    }

    // output layer (H -> 64, identity)
    gemm_bf_kernel<64><<<NPAD / 128, 256, 0, stream>>>(
        xc_x, wT + (size_t)7 * 32768, normb, y);
    gather_fin64<<<NNODES / 4, 256, 0, stream>>>(
        y, row_ptr, sorted_src, normb, b_out, xout);
}